// Round 3
// baseline (480.023 us; speedup 1.0000x reference)
//
#include <hip/hip_runtime.h>
#include <stdint.h>

// ---------------------------------------------------------------------------
// Char segmentation loss — round 3.
// d_out: [0]=loss_low, [1]=loss_middle, [2..)=mask_low (512*27*1024 f32 0/1).
//
// R2 post-mortem: per-pixel cost invariant to block count -> register
// pressure (l[27]+81 accums) caused spills / fragmented loads. R3: LDS tile
// staging (float4 streaming), s2 computed analytically in prep, no max pass.
// ---------------------------------------------------------------------------

static __device__ __forceinline__ float wave_reduce_add(float v) {
  v += __shfl_xor(v, 1, 64);
  v += __shfl_xor(v, 2, 64);
  v += __shfl_xor(v, 4, 64);
  v += __shfl_xor(v, 8, 64);
  v += __shfl_xor(v, 16, 64);
  v += __shfl_xor(v, 32, 64);
  return v;
}

// FROZEN (absmax 0.0 in R1/R2): half-pixel bilinear attention resize + threshold.
static __device__ __forceinline__ uint32_t attn_bits(const float* sattn, float src,
                                                     int lens, float alpha) {
  const int k0 = (int)floorf(src);
  uint32_t bits = 0u;
  if (k0 < 0 || k0 >= 31) {
    const int kk = (k0 < 0) ? 0 : 31;
    for (int c = 0; c < 26; ++c) {
      float v = (c < lens) ? sattn[c * 32 + kk] : 0.0f;
      if (v > alpha) bits |= (1u << c);
    }
  } else {
    const float frac = src - (float)k0;
    const float w1 = frac, w0 = 1.0f - frac;
    for (int c = 0; c < 26; ++c) {
      float v = __fadd_rn(__fmul_rn(w0, sattn[c * 32 + k0]),
                          __fmul_rn(w1, sattn[c * 32 + k0 + 1]));
      v = (c < lens) ? v : 0.0f;
      if (v > alpha) bits |= (1u << c);
    }
  }
  return bits;
}

// FROZEN (absmax 0.0): fm_low 4-tap half-pixel average of fore_mask.
static __device__ __forceinline__ int fm_low_at(const float* fb, int p) {
  const int y = p >> 6;
  const int x = p & 63;
  const float2* fr = (const float2*)(fb + (size_t)(2 * y) * 128 + 2 * x);
  const float2 f0 = fr[0];
  const float2 f1 = fr[64];
  const float t0 = __fadd_rn(0.5f * f0.x, 0.5f * f1.x);
  const float t1 = __fadd_rn(0.5f * f0.y, 0.5f * f1.y);
  const float fmv = __fadd_rn(0.5f * t0, 0.5f * t1);
  return (fmv >= 0.4f) ? 1 : 0;
}

// Prep (512 blocks, 256 thr): attention bits, analytic s2, zero accumulators.
__global__ __launch_bounds__(256) void prep_kernel(
    const float* __restrict__ attn,   // [512,26,32]
    const float* __restrict__ fore,   // [512,4096]
    const int* __restrict__ length,   // [512]
    const float* __restrict__ alpha_p,
    uint32_t* __restrict__ bits_mid,  // [512,128]
    uint32_t* __restrict__ bits_low,  // [512,64]
    float* __restrict__ acc_mid,      // [512,81]: inter[0..26] s1[27..53] s2[54..80]
    float* __restrict__ acc_low,      // [512,81]
    float* __restrict__ ce) {         // [2]
  __shared__ float sattn[832];
  __shared__ int colfm_m[128];
  __shared__ int colfm_l[64];
  __shared__ uint32_t sbm[128];
  __shared__ uint32_t sbl[64];
  const int b = blockIdx.x;
  const int t = threadIdx.x;
  const float* fb = fore + (size_t)b * 4096;

  for (int i = t; i < 832; i += 256) sattn[i] = attn[b * 832 + i];
  if (t < 128) colfm_m[t] = 0;
  if (t < 64) colfm_l[t] = 0;
  __syncthreads();

  // fm column counts (threshold math exact).
  int pm = 0;
  for (int k = 0; k < 16; ++k) pm += (fb[t + 256 * k] >= 0.4f) ? 1 : 0;
  atomicAdd(&colfm_m[t & 127], pm);
  int pl = 0;
  for (int k = 0; k < 4; ++k) pl += fm_low_at(fb, t + 256 * k);
  atomicAdd(&colfm_l[t & 63], pl);

  const float alpha = alpha_p[0];
  const int lens = length[b] - 1;
  if (t < 128) {
    const uint32_t bm = attn_bits(sattn, 0.25f * (float)t - 0.375f, lens, alpha);
    bits_mid[b * 128 + t] = bm;
    sbm[t] = bm;
  } else if (t < 192) {
    const int x = t - 128;
    const uint32_t bl = attn_bits(sattn, 0.5f * (float)x - 0.25f, lens, alpha);
    bits_low[b * 64 + x] = bl;
    sbl[x] = bl;
  }
  __syncthreads();

  if (t < 54) { acc_mid[(size_t)b * 81 + t] = 0.0f; acc_low[(size_t)b * 81 + t] = 0.0f; }
  if (t >= 64 && t < 91) {
    const int c = t - 64;
    int s2m = 0, s2l = 0;
    if (c == 0) {
      int tm = 0, tl = 0;
      for (int x = 0; x < 128; ++x) tm += colfm_m[x];
      for (int x = 0; x < 64; ++x) tl += colfm_l[x];
      s2m = 4096 - tm;
      s2l = 1024 - tl;
    } else {
      for (int x = 0; x < 128; ++x) s2m += colfm_m[x] * (int)((sbm[x] >> (c - 1)) & 1u);
      for (int x = 0; x < 64; ++x) s2l += colfm_l[x] * (int)((sbl[x] >> (c - 1)) & 1u);
    }
    acc_mid[(size_t)b * 81 + 54 + c] = (float)s2m;
    acc_low[(size_t)b * 81 + 54 + c] = (float)s2l;
  }
  if (b == 0 && t == 63) { ce[0] = 0.0f; ce[1] = 0.0f; }
}

// Main: 2560 blocks, interleaved 4 mid : 1 low per group of 5.
// Each block: 4 tiles of 256 px, LDS-staged [27][256] logits.
__global__ __launch_bounds__(256, 4) void main_kernel(
    const float* __restrict__ cf_mid,   // [512,27,4096]
    const float* __restrict__ cf_low,   // [512,27,1024]
    const float* __restrict__ fore,     // [512,4096]
    float* __restrict__ out,
    const uint32_t* __restrict__ bits_mid,
    const uint32_t* __restrict__ bits_low,
    float* __restrict__ acc_mid,
    float* __restrict__ acc_low,
    float* __restrict__ ce) {
  __shared__ float s_tile[27 * 256];   // 27 KB
  __shared__ uint32_t s_bits[128];
  __shared__ float red[4][55];

  const int t = threadIdx.x;
  const int g = blockIdx.x / 5;
  const int r = blockIdx.x % 5;
  const bool low = (r == 4);

  int b, p0, HW;
  const float* cf;
  float* acc;
  if (low) {
    b = g; p0 = 0; HW = 1024;
    cf = cf_low; acc = acc_low;
  } else {
    const int idx = g * 4 + r;
    b = idx >> 2; p0 = (idx & 3) << 10; HW = 4096;
    cf = cf_mid; acc = acc_mid;
  }
  const float* cfb = cf + (size_t)b * 27 * HW;
  const float* fb = fore + (size_t)b * 4096;
  float* mout = out + 2 + (size_t)b * 27 * 1024;  // low only

  if (t < (low ? 64 : 128))
    s_bits[t] = (low ? bits_low + (size_t)b * 64 : bits_mid + (size_t)b * 128)[t];

  float inter[27], s1[27];
#pragma unroll
  for (int c = 0; c < 27; ++c) { inter[c] = 0.0f; s1[c] = 0.0f; }
  float cesum = 0.0f;

  const int wv = t >> 6, ln = t & 63;
  const int xmask = low ? 63 : 127;

  for (int j = 0; j < 4; ++j) {
    const int tp0 = p0 + (j << 8);
    // Stage tile: wave w loads rows c = w, w+4, ... (64 lanes x float4 = row).
    for (int c = wv; c < 27; c += 4) {
      const float4 v = *(const float4*)(cfb + (size_t)c * HW + tp0 + 4 * ln);
      *(float4*)&s_tile[c * 256 + 4 * ln] = v;
    }
    __syncthreads();

    const int p = tp0 + t;
    const uint32_t bits = s_bits[t & xmask];
    const int fmw = low ? fm_low_at(fb, p) : ((fb[p] >= 0.4f) ? 1 : 0);
    const int target = fmw ? (int)__ffs(bits) : 0;

    float e[27];
    float z = 0.0f, lt = 0.0f;
#pragma unroll
    for (int c = 0; c < 27; ++c) {
      const float v = s_tile[c * 256 + t];
      lt = (c == target) ? v : lt;
      const float ee = __expf(v);
      e[c] = ee;
      z += ee;
    }
    const float inv = __builtin_amdgcn_rcpf(z);
    cesum += (__logf(z) - lt);

#pragma unroll
    for (int c = 0; c < 27; ++c) {
      const float prob = e[c] * inv;
      s1[c] += prob;
      float mf;
      if (c == 0) mf = (float)(1 - fmw);
      else mf = (float)(((bits >> (c - 1)) & 1u) & (uint32_t)fmw);
      inter[c] = __fmaf_rn(prob, mf, inter[c]);
      if (low) mout[(size_t)c * 1024 + p] = mf;
    }
    __syncthreads();  // tile consumed; safe to restage
  }

  // Reduction: butterfly over 55 values, cross-wave LDS, atomics to ws.
#pragma unroll
  for (int c = 0; c < 27; ++c) {
    inter[c] = wave_reduce_add(inter[c]);
    s1[c] = wave_reduce_add(s1[c]);
  }
  cesum = wave_reduce_add(cesum);
  if (ln == 0) {
#pragma unroll
    for (int c = 0; c < 27; ++c) {
      red[wv][c] = inter[c];
      red[wv][27 + c] = s1[c];
    }
    red[wv][54] = cesum;
  }
  __syncthreads();
  if (t < 55) {
    const float v = red[0][t] + red[1][t] + red[2][t] + red[3][t];
    if (t == 54) atomicAdd(&ce[low ? 0 : 1], v);
    else atomicAdd(&acc[(size_t)b * 81 + t], v);
  }
}

// Final: block 0 -> loss_low (out[0]), block 1 -> loss_middle (out[1]).
__global__ __launch_bounds__(256) void final_kernel(
    const float* __restrict__ acc_mid,
    const float* __restrict__ acc_low,
    const float* __restrict__ ce,
    const int* __restrict__ length,
    float* __restrict__ out) {
  const int B = blockIdx.x;  // 0=low, 1=mid
  const float* acc = (B == 0) ? acc_low : acc_mid;
  const float hw = (B == 0) ? 1024.0f : 4096.0f;
  const int t = threadIdx.x;
  float dsum = 0.0f;
  for (int b = t; b < 512; b += 256) {
    const int lens = length[b] - 1;
    const float* a = acc + (size_t)b * 81;
    float d = 0.0f;
    for (int c = 1; c < 27; ++c) {
      const float I = a[c], S1 = a[27 + c], S2 = a[54 + c];
      const float score = (2.0f * I + 1.0f) / (S1 + S2 + 1.0f);
      if (c <= lens) d += (1.0f - score);
    }
    dsum += d / (float)lens;
  }
  __shared__ float red[4];
  const int wave = t >> 6, lane = t & 63;
  dsum = wave_reduce_add(dsum);
  if (lane == 0) red[wave] = dsum;
  __syncthreads();
  if (t == 0) {
    const float dice = red[0] + red[1] + red[2] + red[3];
    out[B] = dice * (1.0f / 512.0f) + ce[B] * (1.0f / (512.0f * hw));
  }
}

extern "C" void kernel_launch(void* const* d_in, const int* in_sizes, int n_in,
                              void* d_out, int out_size, void* d_ws, size_t ws_size,
                              hipStream_t stream) {
  const float* cf_mid = (const float*)d_in[0];  // [512,27,32,128]
  const float* cf_low = (const float*)d_in[1];  // [512,27,16,64]
  const float* attn   = (const float*)d_in[2];  // [512,26,32]
  const float* fore   = (const float*)d_in[3];  // [512,1,32,128]
  const int*   length = (const int*)d_in[4];    // [512]
  const float* alpha  = (const float*)d_in[5];  // scalar
  float* out = (float*)d_out;

  uint32_t* bits_mid = (uint32_t*)d_ws;                   // 512*128
  uint32_t* bits_low = bits_mid + 512 * 128;              // 512*64
  float* acc_mid = (float*)(bits_low + 512 * 64);         // 512*81
  float* acc_low = acc_mid + 512 * 81;                    // 512*81
  float* ce = acc_low + 512 * 81;                         // 2

  hipLaunchKernelGGL(prep_kernel, dim3(512), dim3(256), 0, stream,
                     attn, fore, length, alpha, bits_mid, bits_low,
                     acc_mid, acc_low, ce);
  hipLaunchKernelGGL(main_kernel, dim3(2560), dim3(256), 0, stream,
                     cf_mid, cf_low, fore, out, bits_mid, bits_low,
                     acc_mid, acc_low, ce);
  hipLaunchKernelGGL(final_kernel, dim3(2), dim3(256), 0, stream,
                     acc_mid, acc_low, ce, length, out);
}

// Round 4
// 433.862 us; speedup vs baseline: 1.1064x; 1.1064x over previous
//
#include <hip/hip_runtime.h>
#include <stdint.h>

// ---------------------------------------------------------------------------
// Char segmentation loss — round 4.
// d_out: [0]=loss_low, [1]=loss_middle, [2..)=mask_low (512*27*1024 f32 0/1).
//
// R3 post-mortem: __launch_bounds__(256,4) capped VGPR=64 -> ~260 MB spill
// traffic (WRITE 58->243 MB). R4: uncapped, two-pass softmax over LDS tile
// (live regs ~80), fore-mask as ballot bitmasks, mask written by dedicated
// float2 kernel. Main kernel = pure streaming reduce with 7-deep MLP staging.
// ---------------------------------------------------------------------------

static __device__ __forceinline__ float wave_reduce_add(float v) {
  v += __shfl_xor(v, 1, 64);
  v += __shfl_xor(v, 2, 64);
  v += __shfl_xor(v, 4, 64);
  v += __shfl_xor(v, 8, 64);
  v += __shfl_xor(v, 16, 64);
  v += __shfl_xor(v, 32, 64);
  return v;
}

// FROZEN (absmax 0.0 in R1-R3): half-pixel bilinear attention resize + threshold.
static __device__ __forceinline__ uint32_t attn_bits(const float* sattn, float src,
                                                     int lens, float alpha) {
  const int k0 = (int)floorf(src);
  uint32_t bits = 0u;
  if (k0 < 0 || k0 >= 31) {
    const int kk = (k0 < 0) ? 0 : 31;
    for (int c = 0; c < 26; ++c) {
      float v = (c < lens) ? sattn[c * 32 + kk] : 0.0f;
      if (v > alpha) bits |= (1u << c);
    }
  } else {
    const float frac = src - (float)k0;
    const float w1 = frac, w0 = 1.0f - frac;
    for (int c = 0; c < 26; ++c) {
      float v = __fadd_rn(__fmul_rn(w0, sattn[c * 32 + k0]),
                          __fmul_rn(w1, sattn[c * 32 + k0 + 1]));
      v = (c < lens) ? v : 0.0f;
      if (v > alpha) bits |= (1u << c);
    }
  }
  return bits;
}

// FROZEN (absmax 0.0): fm_low 4-tap half-pixel average of fore_mask.
static __device__ __forceinline__ int fm_low_at(const float* fb, int p) {
  const int y = p >> 6;
  const int x = p & 63;
  const float2* fr = (const float2*)(fb + (size_t)(2 * y) * 128 + 2 * x);
  const float2 f0 = fr[0];
  const float2 f1 = fr[64];
  const float t0 = __fadd_rn(0.5f * f0.x, 0.5f * f1.x);
  const float t1 = __fadd_rn(0.5f * f0.y, 0.5f * f1.y);
  const float fmv = __fadd_rn(0.5f * t0, 0.5f * t1);
  return (fmv >= 0.4f) ? 1 : 0;
}

// acc layout per b (stride 82): inter[0..26] s1[27..53] s2[54..80] ce[81]
__global__ __launch_bounds__(256) void prep_kernel(
    const float* __restrict__ attn,    // [512,26,32]
    const float* __restrict__ fore,    // [512,4096]
    const int* __restrict__ length,    // [512]
    const float* __restrict__ alpha_p,
    uint32_t* __restrict__ bits_mid,   // [512,128]
    uint32_t* __restrict__ bits_low,   // [512,64]
    unsigned long long* __restrict__ fmm64,  // [512,64]  fm_mid bits
    unsigned long long* __restrict__ fml64,  // [512,16]  fm_low bits
    float* __restrict__ acc_mid,       // [512,82]
    float* __restrict__ acc_low) {     // [512,82]
  __shared__ float sattn[832];
  __shared__ int colfm_m[128];
  __shared__ int colfm_l[64];
  __shared__ uint32_t sbm[128];
  __shared__ uint32_t sbl[64];
  const int b = blockIdx.x;
  const int t = threadIdx.x;
  const int wv = t >> 6, ln = t & 63;
  const float* fb = fore + (size_t)b * 4096;

  for (int i = t; i < 832; i += 256) sattn[i] = attn[b * 832 + i];
  if (t < 128) colfm_m[t] = 0;
  if (t < 64) colfm_l[t] = 0;
  __syncthreads();

  // fm_mid: per-pixel bits via ballot + column counts (threshold math exact).
  int pm = 0;
  for (int k = 0; k < 16; ++k) {
    const int fm = (fb[t + 256 * k] >= 0.4f) ? 1 : 0;
    pm += fm;
    const unsigned long long bal = __ballot(fm);
    if (ln == 0) fmm64[(size_t)b * 64 + 4 * k + wv] = bal;
  }
  atomicAdd(&colfm_m[t & 127], pm);
  // fm_low likewise.
  int pl = 0;
  for (int k = 0; k < 4; ++k) {
    const int fm = fm_low_at(fb, t + 256 * k);
    pl += fm;
    const unsigned long long bal = __ballot(fm);
    if (ln == 0) fml64[(size_t)b * 16 + 4 * k + wv] = bal;
  }
  atomicAdd(&colfm_l[t & 63], pl);

  const float alpha = alpha_p[0];
  const int lens = length[b] - 1;
  if (t < 128) {
    const uint32_t bm = attn_bits(sattn, 0.25f * (float)t - 0.375f, lens, alpha);
    bits_mid[b * 128 + t] = bm;
    sbm[t] = bm;
  } else if (t < 192) {
    const int x = t - 128;
    const uint32_t bl = attn_bits(sattn, 0.5f * (float)x - 0.25f, lens, alpha);
    bits_low[b * 64 + x] = bl;
    sbl[x] = bl;
  }
  __syncthreads();

  if (t < 54) {
    acc_mid[(size_t)b * 82 + t] = 0.0f;
    acc_low[(size_t)b * 82 + t] = 0.0f;
  }
  if (t == 54) {
    acc_mid[(size_t)b * 82 + 81] = 0.0f;
    acc_low[(size_t)b * 82 + 81] = 0.0f;
  }
  if (t >= 64 && t < 91) {
    const int c = t - 64;
    int s2m = 0, s2l = 0;
    if (c == 0) {
      int tm = 0, tl = 0;
      for (int x = 0; x < 128; ++x) tm += colfm_m[x];
      for (int x = 0; x < 64; ++x) tl += colfm_l[x];
      s2m = 4096 - tm;
      s2l = 1024 - tl;
    } else {
      for (int x = 0; x < 128; ++x) s2m += colfm_m[x] * (int)((sbm[x] >> (c - 1)) & 1u);
      for (int x = 0; x < 64; ++x) s2l += colfm_l[x] * (int)((sbl[x] >> (c - 1)) & 1u);
    }
    acc_mid[(size_t)b * 82 + 54 + c] = (float)s2m;
    acc_low[(size_t)b * 82 + 54 + c] = (float)s2l;
  }
}

// Main: 2560 blocks (groups of 5: 4 mid slices + 1 low batch), 1024 px/block,
// 4 LDS tiles of [27][256]. Two-pass softmax from LDS keeps live regs ~80.
__global__ __launch_bounds__(256) void main_kernel(
    const float* __restrict__ cf_mid,   // [512,27,4096]
    const float* __restrict__ cf_low,   // [512,27,1024]
    const uint32_t* __restrict__ bits_mid,
    const uint32_t* __restrict__ bits_low,
    const unsigned long long* __restrict__ fmm64,
    const unsigned long long* __restrict__ fml64,
    float* __restrict__ acc_mid,
    float* __restrict__ acc_low) {
  __shared__ float s_tile[27 * 256];   // 27 KB
  __shared__ uint32_t s_bits[128];
  __shared__ float red[4][55];

  const int t = threadIdx.x;
  const int wv = t >> 6, ln = t & 63;
  const int g = blockIdx.x / 5, r = blockIdx.x % 5;
  const bool low = (r == 4);

  int b, p0, HW, xmask;
  const float* cf;
  float* acc;
  const uint32_t* bitsg;
  const unsigned long long* fmg;
  if (low) {
    b = g; p0 = 0; HW = 1024; xmask = 63;
    cf = cf_low; acc = acc_low;
    bitsg = bits_low + (size_t)b * 64;
    fmg = fml64 + (size_t)b * 16;
  } else {
    const int idx = g * 4 + r;
    b = idx >> 2; p0 = (idx & 3) << 10; HW = 4096; xmask = 127;
    cf = cf_mid; acc = acc_mid;
    bitsg = bits_mid + (size_t)b * 128;
    fmg = fmm64 + (size_t)b * 64;
  }
  const float* cfb = cf + (size_t)b * 27 * HW;
  if (t <= xmask) s_bits[t] = bitsg[t];  // visible after first __syncthreads

  float inter[27], s1[27];
#pragma unroll
  for (int c = 0; c < 27; ++c) { inter[c] = 0.0f; s1[c] = 0.0f; }
  float cesum = 0.0f;

  for (int j = 0; j < 4; ++j) {
    const int tp0 = p0 + (j << 8);
    // Stage tile: wave wv loads rows c = wv, wv+4, ... (64 lanes x float4/row).
    for (int c = wv; c < 27; c += 4) {
      *(float4*)&s_tile[c * 256 + 4 * ln] =
          *(const float4*)(cfb + (size_t)c * HW + tp0 + 4 * ln);
    }
    __syncthreads();

    const unsigned long long fw = fmg[(tp0 >> 6) + wv];  // wave-uniform word
    const int fm = (int)((fw >> ln) & 1ull);
    const uint32_t bits = s_bits[t & xmask];
    const int target = fm ? (int)__ffs(bits) : 0;

    // Pass A: z and CE.
    float z = 0.0f;
#pragma unroll
    for (int c = 0; c < 27; ++c) z += __expf(s_tile[c * 256 + t]);
    const float lt = s_tile[target * 256 + t];
    cesum += __logf(z) - lt;
    const float inv = __builtin_amdgcn_rcpf(z);

    asm volatile("" ::: "memory");  // forbid exp-CSE across passes (reg diet)

    // Pass B: prob accumulation.
#pragma unroll
    for (int c = 0; c < 27; ++c) {
      const float prob = __expf(s_tile[c * 256 + t]) * inv;
      s1[c] += prob;
      const float mf = (c == 0) ? (float)(1 - fm)
                                : (float)(((bits >> (c - 1)) & 1u) & (uint32_t)fm);
      inter[c] = __fmaf_rn(prob, mf, inter[c]);
    }
    __syncthreads();  // tile consumed; safe to restage
  }

  // Butterfly + cross-wave reduce, then one atomic per (b,slot).
#pragma unroll
  for (int c = 0; c < 27; ++c) {
    inter[c] = wave_reduce_add(inter[c]);
    s1[c] = wave_reduce_add(s1[c]);
  }
  cesum = wave_reduce_add(cesum);
  if (ln == 0) {
#pragma unroll
    for (int c = 0; c < 27; ++c) {
      red[wv][c] = inter[c];
      red[wv][27 + c] = s1[c];
    }
    red[wv][54] = cesum;
  }
  __syncthreads();
  if (t < 55) {
    const float v = red[0][t] + red[1][t] + red[2][t] + red[3][t];
    const int slot = (t == 54) ? 81 : t;
    atomicAdd(&acc[(size_t)b * 82 + slot], v);
  }
}

// Mask writer: 1536 blocks = 512 b x 3 groups of 9 channels; float2 stores
// (d_out+2 is only 8B-aligned, so float4 is out).
__global__ __launch_bounds__(256) void mask_kernel(
    const uint32_t* __restrict__ bits_low,
    const unsigned long long* __restrict__ fml64,
    float* __restrict__ out) {
  __shared__ uint32_t sb[64];
  const int b = blockIdx.x / 3;
  const int c0 = (blockIdx.x % 3) * 9;
  const int t = threadIdx.x;
  if (t < 64) sb[t] = bits_low[(size_t)b * 64 + t];
  __syncthreads();
  const int p = 4 * t;  // pixels p..p+3 (same 64-px fm word)
  const unsigned long long fw = fml64[(size_t)b * 16 + (t >> 4)];
  uint32_t fmv[4], bb[4];
#pragma unroll
  for (int i = 0; i < 4; ++i) {
    fmv[i] = (uint32_t)((fw >> ((p + i) & 63)) & 1ull);
    bb[i] = sb[(p + i) & 63];
  }
  float* mb = out + 2 + (size_t)b * 27648;
  for (int cc = 0; cc < 9; ++cc) {
    const int c = c0 + cc;
    float v[4];
#pragma unroll
    for (int i = 0; i < 4; ++i) {
      v[i] = (c == 0) ? (float)(1u - fmv[i])
                      : (float)(((bb[i] >> (c - 1)) & 1u) & fmv[i]);
    }
    float* dst = mb + (size_t)c * 1024 + p;
    *(float2*)dst = make_float2(v[0], v[1]);
    *(float2*)(dst + 2) = make_float2(v[2], v[3]);
  }
}

// Final: block 0 -> loss_low (out[0]), block 1 -> loss_middle (out[1]).
__global__ __launch_bounds__(256) void final_kernel(
    const float* __restrict__ acc_mid,
    const float* __restrict__ acc_low,
    const int* __restrict__ length,
    float* __restrict__ out) {
  const int B = blockIdx.x;  // 0=low, 1=mid
  const float* acc = (B == 0) ? acc_low : acc_mid;
  const float hw = (B == 0) ? 1024.0f : 4096.0f;
  const int t = threadIdx.x;
  float dsum = 0.0f, csum = 0.0f;
  for (int b = t; b < 512; b += 256) {
    const int lens = length[b] - 1;
    const float* a = acc + (size_t)b * 82;
    float d = 0.0f;
    for (int c = 1; c < 27; ++c) {
      const float I = a[c], S1 = a[27 + c], S2 = a[54 + c];
      const float score = (2.0f * I + 1.0f) / (S1 + S2 + 1.0f);
      if (c <= lens) d += (1.0f - score);
    }
    dsum += d / (float)lens;
    csum += a[81];
  }
  __shared__ float red[4][2];
  const int wave = t >> 6, lane = t & 63;
  dsum = wave_reduce_add(dsum);
  csum = wave_reduce_add(csum);
  if (lane == 0) { red[wave][0] = dsum; red[wave][1] = csum; }
  __syncthreads();
  if (t == 0) {
    const float dice = red[0][0] + red[1][0] + red[2][0] + red[3][0];
    const float ce = red[0][1] + red[1][1] + red[2][1] + red[3][1];
    out[B] = dice * (1.0f / 512.0f) + ce * (1.0f / (512.0f * hw));
  }
}

extern "C" void kernel_launch(void* const* d_in, const int* in_sizes, int n_in,
                              void* d_out, int out_size, void* d_ws, size_t ws_size,
                              hipStream_t stream) {
  const float* cf_mid = (const float*)d_in[0];  // [512,27,32,128]
  const float* cf_low = (const float*)d_in[1];  // [512,27,16,64]
  const float* attn   = (const float*)d_in[2];  // [512,26,32]
  const float* fore   = (const float*)d_in[3];  // [512,1,32,128]
  const int*   length = (const int*)d_in[4];    // [512]
  const float* alpha  = (const float*)d_in[5];  // scalar
  float* out = (float*)d_out;

  uint32_t* bits_mid = (uint32_t*)d_ws;                       // 512*128
  uint32_t* bits_low = bits_mid + 512 * 128;                  // 512*64
  unsigned long long* fmm64 = (unsigned long long*)(bits_low + 512 * 64);  // 512*64
  unsigned long long* fml64 = fmm64 + 512 * 64;               // 512*16
  float* acc_mid = (float*)(fml64 + 512 * 16);                // 512*82
  float* acc_low = acc_mid + 512 * 82;                        // 512*82

  hipLaunchKernelGGL(prep_kernel, dim3(512), dim3(256), 0, stream,
                     attn, fore, length, alpha, bits_mid, bits_low,
                     fmm64, fml64, acc_mid, acc_low);
  hipLaunchKernelGGL(main_kernel, dim3(2560), dim3(256), 0, stream,
                     cf_mid, cf_low, bits_mid, bits_low, fmm64, fml64,
                     acc_mid, acc_low);
  hipLaunchKernelGGL(mask_kernel, dim3(1536), dim3(256), 0, stream,
                     bits_low, fml64, out);
  hipLaunchKernelGGL(final_kernel, dim3(2), dim3(256), 0, stream,
                     acc_mid, acc_low, length, out);
}